// Round 7
// baseline (91.696 us; speedup 1.0000x reference)
//
#include <hip/hip_runtime.h>
#include <hip/hip_bf16.h>

// ContrastiveLoss (SupCon-style), N=4096 rows, K=256 dim, TEMP=0.5.
// loss = mean over same-label off-diag pairs of [log(neg_i + e_ij) - t2_ij],
//   t2_ij = 2*sim_ij, e_ij = exp(t2_ij), neg_i = sum_{lab_j != lab_i} e_ij.
// e_ij <= e^2 ~ 7.4, neg_i >= ~550  ->  log(neg_i+e) = log n + e/n + O(e^2/2n^2);
// the 2nd-order term is <=1e-4 of the scalar -> dropped (R7). Per-row stats:
//   exsum_i = S_{j!=i} e_ij, pexp_i = S_pos e_ij, pt2_i = S_pos t2, pcnt_i.
//   neg_i = exsum_i - pexp_i;  loss = S_i [c log n + pe/n - tt] / S_i c.
//
// R7: R3-R6 plateau at 35-50us with ALL visible pipes <15% busy. The one
// unbudgeted pipe is the per-CU LDS/DS issue pipe: R6 issued ~224 DS ops/wave
// (64 ds_read_b128 + ~160 shfl_xor in the 5-stat x 16-lane reduce) ~ 16us/CU
// serialized — invisible in counters (conflicts=0; it's throughput).
// Fix: stats are SYMMETRIC (e_ij = e_ji exactly) -> accumulate per-COLUMN,
// which reduces over the 4 quads only: 2 shuffles/stat. Wave = 64x64 output
// (4x4 MFMA tiles, dense acc), A/B frags straight from L2-resident packed pk
// (every load = one 1KB coalesced segment). NO LDS, NO barriers, 32 shuffles.
//
// pk layout per 16-row tile (4096 shorts): idx = c*512 + quad*128 + r16*8 + j
//   (row=r16, k=quad*8+c*32+j) == MFMA A/B fragment order. [R3, validated]
// C/D: col = lane&15, row = (lane>>4)*4 + reg  [learn_hip m89/m91].
//
// ws: [0,2MB) pk bf16; [2MB,6MB) part[4][64][4096] f32; [6MB,+8B) acc.

#define N_ROWS 4096
#define K_DIM  256

typedef __attribute__((ext_vector_type(8))) short short8;     // 8 x bf16
typedef __attribute__((ext_vector_type(4))) float float4v;    // MFMA C/D
typedef __attribute__((ext_vector_type(4))) float f4;

#define PK_OFF    0
#define PART_OFF  (N_ROWS * K_DIM * 2)                 // 2 MB
#define ACC_OFF   (PART_OFF + 4 * 64 * N_ROWS * 4)     // +4 MB

// ---------------------------------------------------------------------------
// K1: block = one 16-row tile. Coalesced float4 loads -> LDS, per-row norms
// via 16-lane shuffle groups, coalesced 32B/thread packed-fragment stores.
__global__ void normalize_kernel(const float* __restrict__ emb,
                                 short* __restrict__ pk,
                                 float* __restrict__ acc) {
    int tile = blockIdx.x, t = threadIdx.x;
    __shared__ float lds[16 * 256];
    __shared__ float sc[16];
    const f4* src = (const f4*)(emb + tile * 16 * 256);
    f4* dst4 = (f4*)lds;
    #pragma unroll
    for (int it = 0; it < 4; ++it) dst4[t + 256 * it] = src[t + 256 * it];
    __syncthreads();
    int wave = t >> 6, lane = t & 63;
    int row = wave * 4 + (lane >> 4);          // 4 rows per wave
    float s = 0.f;
    #pragma unroll
    for (int m = 0; m < 16; ++m) {
        float x = lds[row * 256 + (lane & 15) + 16 * m];
        s += x * x;
    }
    s += __shfl_xor(s, 1); s += __shfl_xor(s, 2);
    s += __shfl_xor(s, 4); s += __shfl_xor(s, 8);
    float scale = 1.0f / fmaxf(sqrtf(s), 1e-12f);
    if ((lane & 15) == 0) sc[row] = scale;
    __syncthreads();
    short out[16];
    #pragma unroll
    for (int u = 0; u < 16; ++u) {
        int p = t * 16 + u;
        int j = p & 7, r16 = (p >> 3) & 15, quad = (p >> 7) & 3, c = p >> 9;
        int k = quad * 8 + c * 32 + j;
        float v = lds[r16 * 256 + k] * sc[r16];
        __hip_bfloat16 b = __float2bfloat16(v);
        out[u] = *(short*)&b;
    }
    short* dst = pk + tile * 4096 + t * 16;
    *(short8*)dst = *(short8*)out;
    *(short8*)(dst + 8) = *(short8*)(out + 8);
    if (tile == 0 && t < 2) acc[t] = 0.0f;
}

// ---------------------------------------------------------------------------
// K2: fused sim/exp/stats. Wave = 64x64 output tile (4x4 MFMA tiles).
// Grid 1024 blocks x 4 independent waves = 4096 waves = 64x64 wave-tiles.
// A/B frag loads: pk + tile16*4096 + c*512 + lane*8 (shorts) — 1KB segments.
// Column-stat accumulation (symmetry): reduce = 2 shuffles per stat.
__global__ __launch_bounds__(256, 2)
void negsum_kernel(const short* __restrict__ pk,
                   const int* __restrict__ labels,
                   float* __restrict__ part) {
    int w = threadIdx.x >> 6, lane = threadIdx.x & 63;
    int lane16 = lane & 15, quad = lane >> 4;
    int wid = blockIdx.x * 4 + w;
    int i64 = wid >> 6, j64 = wid & 63;        // 64x64 wave grid
    int ibase = i64 * 64, jbase = j64 * 64;

    // labels for this wave's 64 rows (per-quad view) and 64 cols (per-lane16)
    int labi[16], labj[4];
    #pragma unroll
    for (int it = 0; it < 4; ++it)
        #pragma unroll
        for (int r = 0; r < 4; ++r)
            labi[it * 4 + r] = labels[ibase + it * 16 + quad * 4 + r];
    #pragma unroll
    for (int jt = 0; jt < 4; ++jt)
        labj[jt] = labels[jbase + jt * 16 + lane16];

    float4v acc[4][4];
    #pragma unroll
    for (int a = 0; a < 4; ++a)
        #pragma unroll
        for (int b = 0; b < 4; ++b)
            acc[a][b] = (float4v){0.f, 0.f, 0.f, 0.f};

    // K loop: 8 c-steps of K=32; 8 coalesced 1KB loads + 16 MFMAs per step
    for (int c = 0; c < 8; ++c) {
        short8 af[4], bf[4];
        #pragma unroll
        for (int it = 0; it < 4; ++it)
            af[it] = *(const short8*)(pk + (((i64 * 4 + it) << 12) | (c << 9)) + lane * 8);
        #pragma unroll
        for (int jt = 0; jt < 4; ++jt)
            bf[jt] = *(const short8*)(pk + (((j64 * 4 + jt) << 12) | (c << 9)) + lane * 8);
        #pragma unroll
        for (int it = 0; it < 4; ++it)
            #pragma unroll
            for (int jt = 0; jt < 4; ++jt)
                acc[it][jt] = __builtin_amdgcn_mfma_f32_16x16x32_bf16(
                    af[it], bf[jt], acc[it][jt], 0, 0, 0);
    }

    // epilogue: per-column stats (symmetric == per-row stats)
    float ex[4] = {0,0,0,0}, pe[4] = {0,0,0,0};
    float tt[4] = {0,0,0,0}, pc[4] = {0,0,0,0};
    #pragma unroll
    for (int it = 0; it < 4; ++it) {
        #pragma unroll
        for (int jt = 0; jt < 4; ++jt) {
            int j = jbase + jt * 16 + lane16;
            #pragma unroll
            for (int r = 0; r < 4; ++r) {
                int i = ibase + it * 16 + quad * 4 + r;
                float t2 = 2.0f * acc[it][jt][r];
                float e  = __expf(t2);
                bool keep = (i != j);
                bool same = (labi[it * 4 + r] == labj[jt]);
                ex[jt] += keep ? e : 0.0f;
                float m = (same && keep) ? 1.0f : 0.0f;
                pe[jt] = fmaf(m, e,  pe[jt]);
                tt[jt] = fmaf(m, t2, tt[jt]);
                pc[jt] += m;
            }
        }
    }

    // reduce over the 4 quads (2 shuffles per stat), store partials
    #pragma unroll
    for (int jt = 0; jt < 4; ++jt) {
        float v0 = ex[jt], v1 = pe[jt], v2 = tt[jt], v3 = pc[jt];
        v0 += __shfl_xor(v0, 16); v0 += __shfl_xor(v0, 32);
        v1 += __shfl_xor(v1, 16); v1 += __shfl_xor(v1, 32);
        v2 += __shfl_xor(v2, 16); v2 += __shfl_xor(v2, 32);
        v3 += __shfl_xor(v3, 16); v3 += __shfl_xor(v3, 32);
        if (quad == 0) {
            int col = jbase + jt * 16 + lane16;
            part[((0 * 64 + i64) << 12) + col] = v0;   // part[stat][i64][col]
            part[((1 * 64 + i64) << 12) + col] = v1;
            part[((2 * 64 + i64) << 12) + col] = v2;
            part[((3 * 64 + i64) << 12) + col] = v3;
        }
    }
}

// ---------------------------------------------------------------------------
// K3: per column j (== row j by symmetry): sum 64 partials, closed-form loss,
// block reduce, 2 scalar atomics per block. Grid 16 x 256.
__global__ void rowreduce_kernel(const float* __restrict__ part,
                                 float* __restrict__ acc) {
    int j = blockIdx.x * 256 + threadIdx.x;
    float ex = 0.f, pe = 0.f, tt = 0.f, pc = 0.f;
    for (int ch = 0; ch < 64; ++ch) {
        ex += part[((0 * 64 + ch) << 12) + j];
        pe += part[((1 * 64 + ch) << 12) + j];
        tt += part[((2 * 64 + ch) << 12) + j];
        pc += part[((3 * 64 + ch) << 12) + j];
    }
    float lsum = 0.f;
    if (pc > 0.f) {
        float n = ex - pe;                      // negative-pair sum
        lsum = pc * logf(n) + pe / n - tt;
    } else {
        pc = 0.f;
    }
    #pragma unroll
    for (int off = 32; off > 0; off >>= 1) {
        lsum += __shfl_down(lsum, off, 64);
        pc   += __shfl_down(pc,   off, 64);
    }
    __shared__ float sl[4], sc2[4];
    int wave = threadIdx.x >> 6, lane = threadIdx.x & 63;
    if (lane == 0) { sl[wave] = lsum; sc2[wave] = pc; }
    __syncthreads();
    if (threadIdx.x == 0) {
        atomicAdd(&acc[0], sl[0] + sl[1] + sl[2] + sl[3]);
        atomicAdd(&acc[1], sc2[0] + sc2[1] + sc2[2] + sc2[3]);
    }
}

// ---------------------------------------------------------------------------
__global__ void div_kernel(const float* __restrict__ acc, float* __restrict__ out) {
    if (threadIdx.x == 0) out[0] = acc[0] / acc[1];
}

// ---------------------------------------------------------------------------
extern "C" void kernel_launch(void* const* d_in, const int* in_sizes, int n_in,
                              void* d_out, int out_size, void* d_ws, size_t ws_size,
                              hipStream_t stream) {
    const float* emb    = (const float*)d_in[0];
    const int*   labels = (const int*)d_in[1];
    float* out = (float*)d_out;
    char*  ws  = (char*)d_ws;

    short* pk   = (short*)(ws + PK_OFF);
    float* part = (float*)(ws + PART_OFF);
    float* acc  = (float*)(ws + ACC_OFF);

    normalize_kernel<<<N_ROWS / 16, 256, 0, stream>>>(emb, pk, acc);
    negsum_kernel<<<1024, 256, 0, stream>>>(pk, labels, part);
    rowreduce_kernel<<<16, 256, 0, stream>>>(part, acc);
    div_kernel<<<1, 64, 0, stream>>>(acc, out);
}

// Round 8
// 89.472 us; speedup vs baseline: 1.0249x; 1.0249x over previous
//
#include <hip/hip_runtime.h>
#include <hip/hip_bf16.h>

// ContrastiveLoss (SupCon-style), N=4096 rows, K=256 dim, TEMP=0.5.
// loss = mean over same-label off-diag pairs of [log(neg_i + e_ij) - t2_ij],
//   t2_ij = 2*sim_ij, e_ij = exp(t2_ij), neg_i = sum_{lab_j != lab_i} e_ij.
// e_ij <= e^2 ~ 7.4, neg_i >= ~550 -> log(neg_i+e) = log n + e/n + O(<=1e-4 rel),
// 2nd-order term dropped [R7, absmax stayed 0.0]. Per-row (== per-col, stats
// symmetric since e_ij = e_ji exactly) sums: exsum, pexp, pt2, pcnt;
// neg = exsum - pexp;  loss = S_j [c log n + pe/n - tt] / S_j c.
//
// R8: R3-R7 negsum plateaued 35-46us under FOUR different structures with all
// visible pipes <15% busy. Accounting shows dur_us ~= 41us (ws poison fill) +
// S kernels. This round uses the ONLY staging mechanism with HW-verified
// numbers on gfx950 (m97 ladder, 517->874 TF): global_load_lds width=16 into
// the m97 block shape: block = 128x128 output, 4 waves of 4x4 16x16x32 frags,
// K in 4 BK=64 single-buffered steps (2-barrier loop), 32KB LDS, 3 blocks/CU.
// Also: div fused into rowreduce (ticket + device fence), saving a launch.
//
// pk layout per 16-row tile (4096 shorts): idx = c*512 + quad*128 + r16*8 + j
//   (row=r16, k=quad*8+c*32+j) == MFMA A/B fragment order -> every 1KB chunk
// (tile,c) is 64 lanes x 16B contiguous == exactly one global_load_lds(16).
// C/D: col = lane&15, row = (lane>>4)*4 + reg  [learn_hip m89/m91; R3/R7
// validated absmax 0.0 end-to-end].
//
// ws: [0,2MB) pk bf16; [2MB,6MB) part[4][64][4096] f32; [6MB,+16B) acc[4]
//   (acc[0]=loss_sum, acc[1]=cnt_sum, acc[2]=ticket(int), acc[3]=unused).

#define N_ROWS 4096
#define K_DIM  256

typedef __attribute__((ext_vector_type(8))) short short8;     // 8 x bf16
typedef __attribute__((ext_vector_type(4))) float float4v;    // MFMA C/D
typedef __attribute__((ext_vector_type(4))) float f4;

#define PK_OFF    0
#define PART_OFF  (N_ROWS * K_DIM * 2)                 // 2 MB
#define ACC_OFF   (PART_OFF + 4 * 64 * N_ROWS * 4)     // +4 MB

// async global->LDS, 16B per lane: dest = lds_base + lane*16 (wave-uniform
// base), src = per-lane gptr. [m97-verified path]
__device__ __forceinline__ void gll16(const void* g, void* l) {
    __builtin_amdgcn_global_load_lds(
        (const __attribute__((address_space(1))) unsigned int*)g,
        (__attribute__((address_space(3))) unsigned int*)l, 16, 0, 0);
}

// ---------------------------------------------------------------------------
// K1: block = one 16-row tile. Coalesced float4 loads -> LDS, per-row norms
// via 16-lane shuffle groups, coalesced 32B/thread packed-fragment stores.
__global__ void normalize_kernel(const float* __restrict__ emb,
                                 short* __restrict__ pk,
                                 float* __restrict__ acc) {
    int tile = blockIdx.x, t = threadIdx.x;
    __shared__ float lds[16 * 256];
    __shared__ float sc[16];
    const f4* src = (const f4*)(emb + tile * 16 * 256);
    f4* dst4 = (f4*)lds;
    #pragma unroll
    for (int it = 0; it < 4; ++it) dst4[t + 256 * it] = src[t + 256 * it];
    __syncthreads();
    int wave = t >> 6, lane = t & 63;
    int row = wave * 4 + (lane >> 4);          // 4 rows per wave
    float s = 0.f;
    #pragma unroll
    for (int m = 0; m < 16; ++m) {
        float x = lds[row * 256 + (lane & 15) + 16 * m];
        s += x * x;
    }
    s += __shfl_xor(s, 1); s += __shfl_xor(s, 2);
    s += __shfl_xor(s, 4); s += __shfl_xor(s, 8);
    float scale = 1.0f / fmaxf(sqrtf(s), 1e-12f);
    if ((lane & 15) == 0) sc[row] = scale;
    __syncthreads();
    short out[16];
    #pragma unroll
    for (int u = 0; u < 16; ++u) {
        int p = t * 16 + u;
        int j = p & 7, r16 = (p >> 3) & 15, quad = (p >> 7) & 3, c = p >> 9;
        int k = quad * 8 + c * 32 + j;
        float v = lds[r16 * 256 + k] * sc[r16];
        __hip_bfloat16 b = __float2bfloat16(v);
        out[u] = *(short*)&b;
    }
    short* dst = pk + tile * 4096 + t * 16;
    *(short8*)dst = *(short8*)out;
    *(short8*)(dst + 8) = *(short8*)(out + 8);
    if (tile == 0 && t < 4) acc[t] = 0.0f;     // loss, cnt, ticket, pad
}

// ---------------------------------------------------------------------------
// K2: m97-shaped fused sim/exp/stats. Grid 1024 = 32x32 blocktiles of 128x128.
// 4 waves in a 2x2 grid, each computing a 64x64 subtile (4x4 MFMA frags).
// K = 256 in 4 BK=64 steps: waves 0-1 stage the A-panel (16 x 1KB chunks),
// waves 2-3 the B-panel, via global_load_lds; 2-barrier single-buffer loop.
// Epilogue = per-COLUMN stats (symmetry) -> 2 shuffles/stat, contention-free
// partial stores part[stat][i64][col] (unique writer per slot).
__global__ __launch_bounds__(256, 3)
void negsum_kernel(const short* __restrict__ pk,
                   const int* __restrict__ labels,
                   float* __restrict__ part) {
    __shared__ short As[8192];                 // 16 KB: 16 chunks of 1KB
    __shared__ short Bs[8192];                 // 16 KB
    int t = threadIdx.x;
    int w = t >> 6, lane = t & 63;
    int lane16 = lane & 15, quad = lane >> 4;
    int bi = blockIdx.x >> 5, bj = blockIdx.x & 31;
    int wi = w >> 1, wj = w & 1;

    int ibase = bi * 128 + wi * 64;
    int jbase = bj * 128 + wj * 64;
    int labi[16], labj[4];
    #pragma unroll
    for (int it = 0; it < 4; ++it)
        #pragma unroll
        for (int r = 0; r < 4; ++r)
            labi[it * 4 + r] = labels[ibase + it * 16 + quad * 4 + r];
    #pragma unroll
    for (int jt = 0; jt < 4; ++jt)
        labj[jt] = labels[jbase + jt * 16 + lane16];

    float4v acc[4][4];
    #pragma unroll
    for (int a = 0; a < 4; ++a)
        #pragma unroll
        for (int b = 0; b < 4; ++b)
            acc[a][b] = (float4v){0.f, 0.f, 0.f, 0.f};

    const char* pkb = (const char*)pk;         // tile16 = 8KB, chunk(c) = 1KB

    for (int ks = 0; ks < 4; ++ks) {
        if (ks) __syncthreads();               // LDS safe to overwrite
        if (w < 2) {                           // A-panel: rows bi*128..+128
            #pragma unroll
            for (int u = 0; u < 8; ++u) {
                int a = w * 8 + u, tl = a >> 1, cs = a & 1;
                gll16(pkb + (((bi * 8 + tl) << 13) | ((ks * 2 + cs) << 10)) + lane * 16,
                      (char*)As + (a << 10));
            }
        } else {                               // B-panel: rows bj*128..+128
            #pragma unroll
            for (int u = 0; u < 8; ++u) {
                int a = (w - 2) * 8 + u, tl = a >> 1, cs = a & 1;
                gll16(pkb + (((bj * 8 + tl) << 13) | ((ks * 2 + cs) << 10)) + lane * 16,
                      (char*)Bs + (a << 10));
            }
        }
        __syncthreads();                       // drains vmcnt -> LDS ready
        #pragma unroll
        for (int cs = 0; cs < 2; ++cs) {
            short8 af[4], bf[4];
            #pragma unroll
            for (int it = 0; it < 4; ++it)
                af[it] = *(const short8*)((const char*)As
                         + ((((wi * 4 + it) * 2 + cs) << 10)) + lane * 16);
            #pragma unroll
            for (int jt = 0; jt < 4; ++jt)
                bf[jt] = *(const short8*)((const char*)Bs
                         + ((((wj * 4 + jt) * 2 + cs) << 10)) + lane * 16);
            #pragma unroll
            for (int it = 0; it < 4; ++it)
                #pragma unroll
                for (int jt = 0; jt < 4; ++jt)
                    acc[it][jt] = __builtin_amdgcn_mfma_f32_16x16x32_bf16(
                        af[it], bf[jt], acc[it][jt], 0, 0, 0);
        }
    }

    // epilogue: per-column stats (== per-row by symmetry)
    float ex[4] = {0,0,0,0}, pe[4] = {0,0,0,0};
    float tt[4] = {0,0,0,0}, pc[4] = {0,0,0,0};
    #pragma unroll
    for (int it = 0; it < 4; ++it) {
        #pragma unroll
        for (int jt = 0; jt < 4; ++jt) {
            int j = jbase + jt * 16 + lane16;
            #pragma unroll
            for (int r = 0; r < 4; ++r) {
                int i = ibase + it * 16 + quad * 4 + r;
                float t2 = 2.0f * acc[it][jt][r];
                float e  = __expf(t2);
                bool keep = (i != j);
                bool same = (labi[it * 4 + r] == labj[jt]);
                ex[jt] += keep ? e : 0.0f;
                float m = (same && keep) ? 1.0f : 0.0f;
                pe[jt] = fmaf(m, e,  pe[jt]);
                tt[jt] = fmaf(m, t2, tt[jt]);
                pc[jt] += m;
            }
        }
    }
    int i64 = bi * 2 + wi;                     // this wave's 64-row chunk
    #pragma unroll
    for (int jt = 0; jt < 4; ++jt) {
        float v0 = ex[jt], v1 = pe[jt], v2 = tt[jt], v3 = pc[jt];
        v0 += __shfl_xor(v0, 16); v0 += __shfl_xor(v0, 32);
        v1 += __shfl_xor(v1, 16); v1 += __shfl_xor(v1, 32);
        v2 += __shfl_xor(v2, 16); v2 += __shfl_xor(v2, 32);
        v3 += __shfl_xor(v3, 16); v3 += __shfl_xor(v3, 32);
        if (quad == 0) {
            int col = jbase + jt * 16 + lane16;
            part[((0 * 64 + i64) << 12) + col] = v0;
            part[((1 * 64 + i64) << 12) + col] = v1;
            part[((2 * 64 + i64) << 12) + col] = v2;
            part[((3 * 64 + i64) << 12) + col] = v3;
        }
    }
}

// ---------------------------------------------------------------------------
// K3: per column j: sum 64 partials, closed-form loss, block reduce, 2 scalar
// atomics; LAST block (device-fence ticket) computes the final division.
__global__ void rowreduce_kernel(const float* __restrict__ part,
                                 float* __restrict__ acc,
                                 float* __restrict__ out) {
    int j = blockIdx.x * 256 + threadIdx.x;
    float ex = 0.f, pe = 0.f, tt = 0.f, pc = 0.f;
    for (int ch = 0; ch < 64; ++ch) {
        ex += part[((0 * 64 + ch) << 12) + j];
        pe += part[((1 * 64 + ch) << 12) + j];
        tt += part[((2 * 64 + ch) << 12) + j];
        pc += part[((3 * 64 + ch) << 12) + j];
    }
    float lsum = 0.f;
    if (pc > 0.f) {
        float n = ex - pe;                      // negative-pair sum
        lsum = pc * logf(n) + pe / n - tt;
    } else {
        pc = 0.f;
    }
    #pragma unroll
    for (int off = 32; off > 0; off >>= 1) {
        lsum += __shfl_down(lsum, off, 64);
        pc   += __shfl_down(pc,   off, 64);
    }
    __shared__ float sl[4], sc2[4];
    int wave = threadIdx.x >> 6, lane = threadIdx.x & 63;
    if (lane == 0) { sl[wave] = lsum; sc2[wave] = pc; }
    __syncthreads();
    if (threadIdx.x == 0) {
        atomicAdd(&acc[0], sl[0] + sl[1] + sl[2] + sl[3]);
        atomicAdd(&acc[1], sc2[0] + sc2[1] + sc2[2] + sc2[3]);
        __threadfence();                        // device scope: acc visible
        int ticket = atomicAdd((int*)(acc + 2), 1);
        if (ticket == 15) {                     // last block finalizes
            float ls = atomicAdd(&acc[0], 0.0f);  // coherent read via RMW
            float cs = atomicAdd(&acc[1], 0.0f);
            out[0] = ls / cs;
        }
    }
}

// ---------------------------------------------------------------------------
extern "C" void kernel_launch(void* const* d_in, const int* in_sizes, int n_in,
                              void* d_out, int out_size, void* d_ws, size_t ws_size,
                              hipStream_t stream) {
    const float* emb    = (const float*)d_in[0];
    const int*   labels = (const int*)d_in[1];
    float* out = (float*)d_out;
    char*  ws  = (char*)d_ws;

    short* pk   = (short*)(ws + PK_OFF);
    float* part = (float*)(ws + PART_OFF);
    float* acc  = (float*)(ws + ACC_OFF);

    normalize_kernel<<<N_ROWS / 16, 256, 0, stream>>>(emb, pk, acc);
    negsum_kernel<<<1024, 256, 0, stream>>>(pk, labels, part);
    rowreduce_kernel<<<16, 256, 0, stream>>>(part, acc, out);
}

// Round 9
// 81.306 us; speedup vs baseline: 1.1278x; 1.1004x over previous
//
#include <hip/hip_runtime.h>
#include <hip/hip_bf16.h>

// ContrastiveLoss (SupCon-style), N=4096 rows, K=256 dim, TEMP=0.5.
// loss = mean over same-label off-diag pairs of [log(neg_i + e_ij) - t2_ij],
//   t2_ij = 2*sim_ij, e_ij = exp(t2_ij), neg_i = sum_{lab_j != lab_i} e_ij.
// e_ij <= e^2 ~ 7.4, neg_i >= ~550 -> log(neg_i+e) = log n + e/n (2nd-order
// dropped, <=1e-4 rel [R7, absmax stayed 0]). Stats are symmetric (e_ij=e_ji)
// -> accumulate per-COLUMN: exsum, pexp, pt2, pcnt; neg = exsum - pexp;
// loss = S_j [c log n + pe/n - tt] / S_j c.
//
// R9: R3-R8 — FIVE different negsum structures all plateau 35-46us with
// MFMA/VALU/HBM busy-time summing to <10us -> the wall scales with
// memory-side TRANSACTION VOLUME (requests x latency under a concurrency
// cap), not structure. Lever: fp8 e4m3 operands. mfma_f32_16x16x32_fp8_fp8
// = bf16 rate, 8B/lane per frag; pairing two K=32 c-steps per 16B load
// HALVES staging requests (32->16 gll16), ds_reads (64->32), pk (2->1MB),
// and L2 bytes. Elements scaled x8 (avoids e4m3 subnormals; max 8 << 448);
// acc = 64*sim -> t2 = acc/32 exact. Convert via v_cvt_pk_fp8_f32 HW
// builtin — gfx950 HW fp8 is OCP on both convert and MFMA sides.
//
// pk8 layout per 16-row tile (4096 B):
//   byte[u*1024 + quad*256 + r16*16 + h*8 + j] = fp8(norm8[r16][quad*8+(2u+h)*32+j])
// -> per (tile,u): one 1KB chunk = 64 lanes x 16B = one gll16; lane's 16B =
// the K=32 fragments for c-steps {2u, 2u+1} (k_local = quad*8 + j).
// C/D: col = lane&15, row = (lane>>4)*4 + reg  [learn_hip m89/m91; R3-R8
// validated absmax 0.0 end-to-end].
//
// ws: [0,1MB) pk8; [2MB,6MB) part[4][64][4096] f32; [6MB,+16B) acc[4]
//   (acc[0]=loss_sum, acc[1]=cnt_sum, acc[2]=ticket, acc[3]=pad).

#define N_ROWS 4096
#define K_DIM  256

typedef __attribute__((ext_vector_type(4))) float float4v;    // MFMA C/D
typedef __attribute__((ext_vector_type(4))) float f4;
typedef __attribute__((ext_vector_type(4))) int   int4v;
typedef __attribute__((ext_vector_type(2))) long  long2v;     // 2 x 8B frags

#define PK_OFF    0
#define PART_OFF  (2 * 1024 * 1024)
#define ACC_OFF   (PART_OFF + 4 * 64 * N_ROWS * 4)     // +4 MB

// async global->LDS, 16B/lane: dest = wave-uniform base + lane*16 [m97 path]
__device__ __forceinline__ void gll16(const void* g, void* l) {
    __builtin_amdgcn_global_load_lds(
        (const __attribute__((address_space(1))) unsigned int*)g,
        (__attribute__((address_space(3))) unsigned int*)l, 16, 0, 0);
}

// ---------------------------------------------------------------------------
// K1: block = one 16-row tile. Coalesced float4 loads -> LDS, per-row norms
// via 16-lane shuffle groups, x8-scaled fp8 pack, 16B/thread coalesced store.
__global__ void normalize_kernel(const float* __restrict__ emb,
                                 unsigned char* __restrict__ pk8,
                                 float* __restrict__ acc) {
    int tile = blockIdx.x, t = threadIdx.x;
    __shared__ float lds[16 * 256];
    __shared__ float sc[16];
    const f4* src = (const f4*)(emb + tile * 16 * 256);
    f4* dst4 = (f4*)lds;
    #pragma unroll
    for (int it = 0; it < 4; ++it) dst4[t + 256 * it] = src[t + 256 * it];
    __syncthreads();
    int wave = t >> 6, lane = t & 63;
    int row = wave * 4 + (lane >> 4);          // 4 rows per wave
    float s = 0.f;
    #pragma unroll
    for (int m = 0; m < 16; ++m) {
        float x = lds[row * 256 + (lane & 15) + 16 * m];
        s += x * x;
    }
    s += __shfl_xor(s, 1); s += __shfl_xor(s, 2);
    s += __shfl_xor(s, 4); s += __shfl_xor(s, 8);
    float scale = 1.0f / fmaxf(sqrtf(s), 1e-12f);
    if ((lane & 15) == 0) sc[row] = scale;
    __syncthreads();
    // pack 16 bytes: fixed (u, quad, r16) per thread; h,j sweep the 16B
    int u = t >> 6, quad = (t >> 4) & 3, r16 = t & 15;
    float s8 = sc[r16] * 8.0f;
    const float* lr = lds + r16 * 256;
    int4v wv;
    #pragma unroll
    for (int wi = 0; wi < 4; ++wi) {           // word wi = bytes 4wi..4wi+3
        int h  = wi >> 1;                      // bytes 0-7: h=0, 8-15: h=1
        int j0 = (wi & 1) * 4;
        int kb = quad * 8 + (2 * u + h) * 32 + j0;
        float v0 = lr[kb + 0] * s8, v1 = lr[kb + 1] * s8;
        float v2 = lr[kb + 2] * s8, v3 = lr[kb + 3] * s8;
        int wd = __builtin_amdgcn_cvt_pk_fp8_f32(v0, v1, 0, 0);
        wd     = __builtin_amdgcn_cvt_pk_fp8_f32(v2, v3, wd, 1);
        wv[wi] = wd;
    }
    *(int4v*)(pk8 + tile * 4096 + t * 16) = wv;
    if (tile == 0 && t < 4) acc[t] = 0.0f;     // loss, cnt, ticket, pad
}

// ---------------------------------------------------------------------------
// K2: fp8 fused sim/exp/stats, m97 shape. Grid 1024 = 32x32 tiles of 128x128.
// 4 waves in 2x2, each a 64x64 subtile (4x4 MFMA frags). K=256 in 4 BK=64
// steps: waves 0-1 stage A-panel (8x1KB), waves 2-3 B-panel via gll16;
// 8KB+8KB LDS. Per ks: 8 ds_read_b128 (each = 2 c-step frags) + 32 MFMAs.
// Epilogue: per-column stats, 2 shuffles/stat, contention-free partials.
__global__ __launch_bounds__(256, 3)
void negsum_kernel(const unsigned char* __restrict__ pk8,
                   const int* __restrict__ labels,
                   float* __restrict__ part) {
    __shared__ __align__(16) unsigned char As8[8192];
    __shared__ __align__(16) unsigned char Bs8[8192];
    int t = threadIdx.x;
    int w = t >> 6, lane = t & 63;
    int lane16 = lane & 15, quad = lane >> 4;
    int bi = blockIdx.x >> 5, bj = blockIdx.x & 31;
    int wi = w >> 1, wj = w & 1;

    int ibase = bi * 128 + wi * 64;
    int jbase = bj * 128 + wj * 64;
    int labi[16], labj[4];
    #pragma unroll
    for (int it = 0; it < 4; ++it)
        #pragma unroll
        for (int r = 0; r < 4; ++r)
            labi[it * 4 + r] = labels[ibase + it * 16 + quad * 4 + r];
    #pragma unroll
    for (int jt = 0; jt < 4; ++jt)
        labj[jt] = labels[jbase + jt * 16 + lane16];

    float4v acc[4][4];
    #pragma unroll
    for (int a = 0; a < 4; ++a)
        #pragma unroll
        for (int b = 0; b < 4; ++b)
            acc[a][b] = (float4v){0.f, 0.f, 0.f, 0.f};

    const char* pkb = (const char*)pk8;        // tile16 = 4KB, chunk(u) = 1KB

    for (int ks = 0; ks < 4; ++ks) {
        if (ks) __syncthreads();
        if (w < 2) {                           // A-panel: tiles bi*8..+8
            #pragma unroll
            for (int u = 0; u < 4; ++u) {
                int tl = w * 4 + u;
                gll16(pkb + (((bi * 8 + tl) << 12) | (ks << 10)) + lane * 16,
                      As8 + (tl << 10));
            }
        } else {                               // B-panel: tiles bj*8..+8
            #pragma unroll
            for (int u = 0; u < 4; ++u) {
                int tl = (w - 2) * 4 + u;
                gll16(pkb + (((bj * 8 + tl) << 12) | (ks << 10)) + lane * 16,
                      Bs8 + (tl << 10));
            }
        }
        __syncthreads();                       // drains vmcnt -> LDS ready
        long2v av[4], bv[4];
        #pragma unroll
        for (int it = 0; it < 4; ++it)
            av[it] = *(const long2v*)(As8 + (((wi * 4 + it) << 10)) + lane * 16);
        #pragma unroll
        for (int jt = 0; jt < 4; ++jt)
            bv[jt] = *(const long2v*)(Bs8 + (((wj * 4 + jt) << 10)) + lane * 16);
        #pragma unroll
        for (int h = 0; h < 2; ++h)
            #pragma unroll
            for (int it = 0; it < 4; ++it)
                #pragma unroll
                for (int jt = 0; jt < 4; ++jt)
                    acc[it][jt] = __builtin_amdgcn_mfma_f32_16x16x32_fp8_fp8(
                        av[it][h], bv[jt][h], acc[it][jt], 0, 0, 0);
    }

    // epilogue: per-column stats (== per-row by symmetry); acc = 64*sim
    float ex[4] = {0,0,0,0}, pe[4] = {0,0,0,0};
    float tt[4] = {0,0,0,0}, pc[4] = {0,0,0,0};
    #pragma unroll
    for (int it = 0; it < 4; ++it) {
        #pragma unroll
        for (int jt = 0; jt < 4; ++jt) {
            int j = jbase + jt * 16 + lane16;
            #pragma unroll
            for (int r = 0; r < 4; ++r) {
                int i = ibase + it * 16 + quad * 4 + r;
                float t2 = acc[it][jt][r] * 0.03125f;   // 2*sim, exact pow2
                float e  = __expf(t2);
                bool keep = (i != j);
                bool same = (labi[it * 4 + r] == labj[jt]);
                ex[jt] += keep ? e : 0.0f;
                float m = (same && keep) ? 1.0f : 0.0f;
                pe[jt] = fmaf(m, e,  pe[jt]);
                tt[jt] = fmaf(m, t2, tt[jt]);
                pc[jt] += m;
            }
        }
    }
    int i64 = bi * 2 + wi;                     // this wave's 64-row chunk
    #pragma unroll
    for (int jt = 0; jt < 4; ++jt) {
        float v0 = ex[jt], v1 = pe[jt], v2 = tt[jt], v3 = pc[jt];
        v0 += __shfl_xor(v0, 16); v0 += __shfl_xor(v0, 32);
        v1 += __shfl_xor(v1, 16); v1 += __shfl_xor(v1, 32);
        v2 += __shfl_xor(v2, 16); v2 += __shfl_xor(v2, 32);
        v3 += __shfl_xor(v3, 16); v3 += __shfl_xor(v3, 32);
        if (quad == 0) {
            int col = jbase + jt * 16 + lane16;
            part[((0 * 64 + i64) << 12) + col] = v0;
            part[((1 * 64 + i64) << 12) + col] = v1;
            part[((2 * 64 + i64) << 12) + col] = v2;
            part[((3 * 64 + i64) << 12) + col] = v3;
        }
    }
}

// ---------------------------------------------------------------------------
// K3: per column j: sum 64 partials, closed-form loss, block reduce, 2 scalar
// atomics; LAST block (device-fence ticket) computes the final division.
__global__ void rowreduce_kernel(const float* __restrict__ part,
                                 float* __restrict__ acc,
                                 float* __restrict__ out) {
    int j = blockIdx.x * 256 + threadIdx.x;
    float ex = 0.f, pe = 0.f, tt = 0.f, pc = 0.f;
    for (int ch = 0; ch < 64; ++ch) {
        ex += part[((0 * 64 + ch) << 12) + j];
        pe += part[((1 * 64 + ch) << 12) + j];
        tt += part[((2 * 64 + ch) << 12) + j];
        pc += part[((3 * 64 + ch) << 12) + j];
    }
    float lsum = 0.f;
    if (pc > 0.f) {
        float n = ex - pe;                      // negative-pair sum
        lsum = pc * logf(n) + pe / n - tt;
    } else {
        pc = 0.f;
    }
    #pragma unroll
    for (int off = 32; off > 0; off >>= 1) {
        lsum += __shfl_down(lsum, off, 64);
        pc   += __shfl_down(pc,   off, 64);
    }
    __shared__ float sl[4], sc2[4];
    int wave = threadIdx.x >> 6, lane = threadIdx.x & 63;
    if (lane == 0) { sl[wave] = lsum; sc2[wave] = pc; }
    __syncthreads();
    if (threadIdx.x == 0) {
        atomicAdd(&acc[0], sl[0] + sl[1] + sl[2] + sl[3]);
        atomicAdd(&acc[1], sc2[0] + sc2[1] + sc2[2] + sc2[3]);
        __threadfence();
        int ticket = atomicAdd((int*)(acc + 2), 1);
        if (ticket == 15) {
            float ls = atomicAdd(&acc[0], 0.0f);
            float cs = atomicAdd(&acc[1], 0.0f);
            out[0] = ls / cs;
        }
    }
}

// ---------------------------------------------------------------------------
extern "C" void kernel_launch(void* const* d_in, const int* in_sizes, int n_in,
                              void* d_out, int out_size, void* d_ws, size_t ws_size,
                              hipStream_t stream) {
    const float* emb    = (const float*)d_in[0];
    const int*   labels = (const int*)d_in[1];
    float* out = (float*)d_out;
    char*  ws  = (char*)d_ws;

    unsigned char* pk8  = (unsigned char*)(ws + PK_OFF);
    float*         part = (float*)(ws + PART_OFF);
    float*         acc  = (float*)(ws + ACC_OFF);

    normalize_kernel<<<N_ROWS / 16, 256, 0, stream>>>(emb, pk8, acc);
    negsum_kernel<<<1024, 256, 0, stream>>>(pk8, labels, part);
    rowreduce_kernel<<<16, 256, 0, stream>>>(part, acc, out);
}